// Round 2
// baseline (47124.048 us; speedup 1.0000x reference)
//
#include <hip/hip_runtime.h>
#include <hip/hip_bf16.h>

#define SS 128
#define TT 128
#define NBLK 256

__device__ __forceinline__ float sigf(float x) { return 1.f / (1.f + __expf(-x)); }

// ---------------------------------------------------------------------------
// Device-wide barrier (grid must be exactly NBLK co-resident blocks).
__device__ __forceinline__ void gbar(unsigned* bar) {
  __syncthreads();
  if (threadIdx.x == 0) {
    __threadfence();
    unsigned g = __hip_atomic_load(&bar[1], __ATOMIC_RELAXED, __HIP_MEMORY_SCOPE_AGENT);
    unsigned old = __hip_atomic_fetch_add(&bar[0], 1u, __ATOMIC_ACQ_REL, __HIP_MEMORY_SCOPE_AGENT);
    if (old == NBLK - 1u) {
      __hip_atomic_store(&bar[0], 0u, __ATOMIC_RELAXED, __HIP_MEMORY_SCOPE_AGENT);
      __hip_atomic_fetch_add(&bar[1], 1u, __ATOMIC_RELEASE, __HIP_MEMORY_SCOPE_AGENT);
    } else {
      while (__hip_atomic_load(&bar[1], __ATOMIC_ACQUIRE, __HIP_MEMORY_SCOPE_AGENT) == g)
        __builtin_amdgcn_s_sleep(2);
    }
    __threadfence();
  }
  __syncthreads();
}

// interleaved-4 transposed activation layout: element (row r, batch b) at
// (r>>2)*256 + b*4 + (r&3)  -> lane b loads float4 = rows r..r+3 coalesced.
__device__ __forceinline__ int idx4(int r, int b) {
  return (r >> 2) * 256 + b * 4 + (r & 3);
}

template<int NJ, int NK4>
__device__ __forceinline__ void mac_rows(const float* __restrict__ xb,
                                         const float* const* wr, float* acc) {
#pragma unroll 2
  for (int k4 = 0; k4 < NK4; ++k4) {
    float4 xv = *(const float4*)(xb + (size_t)k4 * 256);
#pragma unroll
    for (int j = 0; j < NJ; ++j) {
      float4 w4 = *(const float4*)(wr[j] + k4 * 4);
      acc[j] += xv.x * w4.x + xv.y * w4.y + xv.z * w4.z + xv.w * w4.w;
    }
  }
}

// ---------------------------------------------------------------------------
__global__ void k_embed(const float* __restrict__ emb, const int* __restrict__ toks,
                        float* __restrict__ out, int seqlen) {
  int s = blockIdx.x >> 6, b = blockIdx.x & 63;
  int tok = toks[b * seqlen + s];
  const float4* src = (const float4*)(emb + (size_t)tok * 512);
  float4* dst = (float4*)(out + (size_t)blockIdx.x * 512);
  dst[threadIdx.x] = src[threadIdx.x];
}

// ---------------------------------------------------------------------------
// GEMM C[m][n] = X[m]·W[n] + b1[n] + b2[n].
// MODE 1: write GT[((m>>6)*ldc + n)*64 + (m&63)]   (per-timestep transposed gates)
// MODE 2: write out[((m&63)*512 + n)*128 + (m>>6)] (final [B][OUT][T])
template<int MODE>
__global__ __launch_bounds__(256) void k_gemm(
    const float* __restrict__ X, int ldx,
    const float* __restrict__ W, int ldw, int koff,
    const float* __restrict__ b1, const float* __restrict__ b2,
    float* __restrict__ C, int ldc, int K) {
  __shared__ float Xs[16][132];
  __shared__ float Ws[16][132];
  int m0 = blockIdx.y * 128, n0 = blockIdx.x * 128;
  int tx = threadIdx.x & 15, ty = threadIdx.x >> 4;
  float acc[8][8] = {};
  for (int k0 = 0; k0 < K; k0 += 16) {
    __syncthreads();
#pragma unroll
    for (int j = 0; j < 2; ++j) {
      int f4 = threadIdx.x + j * 256;
      int row = f4 >> 2, kc = (f4 & 3) * 4;
      float4 xv = *(const float4*)&X[(size_t)(m0 + row) * ldx + k0 + kc];
      Xs[kc + 0][row] = xv.x; Xs[kc + 1][row] = xv.y;
      Xs[kc + 2][row] = xv.z; Xs[kc + 3][row] = xv.w;
      float4 wv = *(const float4*)&W[(size_t)(n0 + row) * ldw + koff + k0 + kc];
      Ws[kc + 0][row] = wv.x; Ws[kc + 1][row] = wv.y;
      Ws[kc + 2][row] = wv.z; Ws[kc + 3][row] = wv.w;
    }
    __syncthreads();
#pragma unroll
    for (int kk = 0; kk < 16; ++kk) {
      float a[8], w[8];
      *(float4*)&a[0] = *(const float4*)&Xs[kk][ty * 8];
      *(float4*)&a[4] = *(const float4*)&Xs[kk][ty * 8 + 4];
      *(float4*)&w[0] = *(const float4*)&Ws[kk][tx * 8];
      *(float4*)&w[4] = *(const float4*)&Ws[kk][tx * 8 + 4];
#pragma unroll
      for (int i = 0; i < 8; ++i)
#pragma unroll
        for (int j = 0; j < 8; ++j)
          acc[i][j] += a[i] * w[j];
    }
  }
  float bias[8];
#pragma unroll
  for (int j = 0; j < 8; ++j) {
    int n = n0 + tx * 8 + j;
    bias[j] = (b1 ? b1[n] : 0.f) + (b2 ? b2[n] : 0.f);
  }
  for (int i = 0; i < 8; ++i) {
    int m = m0 + ty * 8 + i;
#pragma unroll
    for (int j = 0; j < 8; ++j) {
      int n = n0 + tx * 8 + j;
      float v = acc[i][j] + bias[j];
      if (MODE == 1)
        C[((size_t)(m >> 6) * ldc + n) * 64 + (m & 63)] = v;
      else
        C[((size_t)(m & 63) * 512 + n) * 128 + (m >> 6)] = v;
    }
  }
}

// ---------------------------------------------------------------------------
// Persistent encoder layer: 128 steps, both directions, 1 grid-sync per step.
// Block nb: dir d = nb>>7, covers gate cols {nbL + 128j} = 4 gates x hu in {nbL, nbL+128}.
__global__ __launch_bounds__(256, 1) void enc_persist(
    const float* __restrict__ GT,     // [128][2048][64] precomputed input gates (biases folded)
    const float* __restrict__ whh,    // [2][1024][256] this layer
    float* __restrict__ hI,           // [2 parity][2 dir][64 r4][256] recurrent h (interleaved-4)
    float* __restrict__ lout,         // [8192][512] row-major layer output
    float* __restrict__ hFin,         // xI dest base: write rows 512 + d*256 + hu (parity 0)
    float* __restrict__ cFin,         // [512][64]
    unsigned* bar) {
  int nb = blockIdx.x;
  int d = nb >> 7, nbL = nb & 127;
  int tid = threadIdx.x;
  int lane = tid & 63;
  int wv = __builtin_amdgcn_readfirstlane(tid >> 6);
  __shared__ float pt[4][8][64];
  float creg = 0.f;
  const float* wr[8];
#pragma unroll
  for (int j = 0; j < 8; ++j)
    wr[j] = whh + ((size_t)(d * 1024 + nbL + 128 * j)) * 256 + wv * 64;

  for (int t = 0; t < SS; ++t) {
    int pp = t & 1;
    if (t > 0) {
      const float* xb = hI + (pp * 2 + d) * 16384 + wv * 4096 + lane * 4;
      float acc[8] = {};
      mac_rows<8, 16>(xb, wr, acc);
#pragma unroll
      for (int j = 0; j < 8; ++j) pt[wv][j][lane] = acc[j];
    }
    __syncthreads();
    if (tid < 128) {
      int b = tid & 63, hi = tid >> 6;
      int hu = nbL + hi * 128;
      int s = d ? (SS - 1 - t) : t;
      float g4[4];
#pragma unroll
      for (int g = 0; g < 4; ++g) {
        float sum = GT[((size_t)s * 2048 + d * 1024 + g * 256 + hu) * 64 + b];
        if (t > 0)
          sum += pt[0][2 * g + hi][b] + pt[1][2 * g + hi][b] +
                 pt[2][2 * g + hi][b] + pt[3][2 * g + hi][b];
        g4[g] = sum;
      }
      float ig = sigf(g4[0]), fg = sigf(g4[1]), gg = tanhf(g4[2]), og = sigf(g4[3]);
      creg = fg * creg + ig * gg;
      float hn = og * tanhf(creg);
      hI[((pp ^ 1) * 2 + d) * 16384 + idx4(hu, b)] = hn;
      lout[((size_t)s * 64 + b) * 512 + d * 256 + hu] = hn;
      if (t == SS - 1) {
        hFin[idx4(512 + d * 256 + hu, b)] = hn;
        cFin[(d * 256 + hu) * 64 + b] = creg;
      }
    }
    if (t < SS - 1) gbar(bar);
  }
}

// ---------------------------------------------------------------------------
// Persistent decoder: 128 steps x 4 phases (cell0, cell1, attention, outproj).
// Cell phases: block nb covers cols {nb + 256j} = 4 gates x hu in {nb, nb+256}.
__global__ __launch_bounds__(256, 1) void dec_persist(
    const float* __restrict__ GdT,    // [128][2048][64] emb gates (biases 0 folded)
    const float* __restrict__ w_ih0,  // [2048][1024]
    const float* __restrict__ w_hh0,  // [2048][512]
    const float* __restrict__ w_ih1,  // [2048][512]
    const float* __restrict__ w_hh1,  // [2048][512]
    const float* __restrict__ b_ih1, const float* __restrict__ b_hh1,
    const float* __restrict__ attn_w, // [512][1024]
    const float* __restrict__ enc_out,// [8192][512] row-major
    const int* __restrict__ src_tokens,
    const float* __restrict__ c0T, const float* __restrict__ c1T,  // [512][64]
    float* __restrict__ x0I,          // [2][256 r4][256]: rows 0-511 feed, 512-1023 h0
    float* __restrict__ x1I,          // [2][256 r4][256]: rows 0-511 h0cur, 512-1023 h1
    float* __restrict__ x2I,          // [128 r4][256]: ctx
    float* __restrict__ houts,        // [8192][512] row-major
    unsigned* bar) {
  int nb = blockIdx.x;
  int tid = threadIdx.x;
  int lane = tid & 63;
  int wv = __builtin_amdgcn_readfirstlane(tid >> 6);
  __shared__ float pt[4][8][64];
  __shared__ float h1s[512];
  __shared__ float sc[128];

  int bb = tid & 63, hi = tid >> 6;
  int hu = nb + (hi & 1) * 256;
  float c0r = 0.f, c1r = 0.f;
  if (tid < 128) { c0r = c0T[hu * 64 + bb]; c1r = c1T[hu * 64 + bb]; }

  const float* wrA[8]; const float* wrB[8]; const float* wrD[2];
  if (wv < 2) {
#pragma unroll
    for (int j = 0; j < 8; ++j) {
      wrA[j] = w_ih0 + (size_t)(nb + 256 * j) * 1024 + 512 + wv * 256;
      wrB[j] = w_ih1 + (size_t)(nb + 256 * j) * 512 + wv * 256;
    }
#pragma unroll
    for (int j = 0; j < 2; ++j)
      wrD[j] = attn_w + (size_t)(nb * 2 + j) * 1024 + wv * 256;
  } else {
#pragma unroll
    for (int j = 0; j < 8; ++j) {
      wrA[j] = w_hh0 + (size_t)(nb + 256 * j) * 512 + (wv - 2) * 256;
      wrB[j] = w_hh1 + (size_t)(nb + 256 * j) * 512 + (wv - 2) * 256;
    }
#pragma unroll
    for (int j = 0; j < 2; ++j)
      wrD[j] = attn_w + (size_t)(nb * 2 + j) * 1024 + 512 + (wv - 2) * 256;
  }

  for (int t = 0; t < TT; ++t) {
    int pp = t & 1;
    // ---- A: cell0 gates ----
    {
      const float* xb = x0I + pp * 65536 + wv * 16384 + lane * 4;
      float acc[8] = {};
      mac_rows<8, 64>(xb, wrA, acc);
#pragma unroll
      for (int j = 0; j < 8; ++j) pt[wv][j][lane] = acc[j];
    }
    __syncthreads();
    if (tid < 128) {
      float g4[4];
#pragma unroll
      for (int g = 0; g < 4; ++g)
        g4[g] = pt[0][2 * g + hi][bb] + pt[1][2 * g + hi][bb] +
                pt[2][2 * g + hi][bb] + pt[3][2 * g + hi][bb] +
                GdT[((size_t)t * 2048 + g * 512 + hu) * 64 + bb];
      float ig = sigf(g4[0]), fg = sigf(g4[1]), gg = tanhf(g4[2]), og = sigf(g4[3]);
      c0r = fg * c0r + ig * gg;
      float hn = og * tanhf(c0r);
      x0I[(pp ^ 1) * 65536 + idx4(512 + hu, bb)] = hn;
      x1I[pp * 65536 + idx4(hu, bb)] = hn;
    }
    gbar(bar);
    // ---- B: cell1 gates ----
    {
      const float* xb = x1I + pp * 65536 + wv * 16384 + lane * 4;
      float acc[8] = {};
      mac_rows<8, 64>(xb, wrB, acc);
#pragma unroll
      for (int j = 0; j < 8; ++j) pt[wv][j][lane] = acc[j];
    }
    __syncthreads();
    if (tid < 128) {
      float g4[4];
#pragma unroll
      for (int g = 0; g < 4; ++g)
        g4[g] = pt[0][2 * g + hi][bb] + pt[1][2 * g + hi][bb] +
                pt[2][2 * g + hi][bb] + pt[3][2 * g + hi][bb] +
                b_ih1[g * 512 + hu] + b_hh1[g * 512 + hu];
      float ig = sigf(g4[0]), fg = sigf(g4[1]), gg = tanhf(g4[2]), og = sigf(g4[3]);
      c1r = fg * c1r + ig * gg;
      float hn = og * tanhf(c1r);
      x1I[(pp ^ 1) * 65536 + idx4(512 + hu, bb)] = hn;
    }
    gbar(bar);
    // ---- C: attention (blocks 0..63, one per batch) ----
    if (nb < 64) {
      const float* x1c = x1I + (pp ^ 1) * 65536;
      for (int i = tid; i < 512; i += 256)
        h1s[i] = x1c[idx4(512 + i, nb)];
      __syncthreads();
      {
        int s2 = tid >> 1, half = tid & 1;
        const float* er = enc_out + ((size_t)s2 * 64 + nb) * 512 + half * 256;
        const float* hh = h1s + half * 256;
        float a = 0.f;
#pragma unroll 8
        for (int k = 0; k < 256; k += 4) {
          float4 ev = *(const float4*)&er[k];
          a += ev.x * hh[k] + ev.y * hh[k + 1] + ev.z * hh[k + 2] + ev.w * hh[k + 3];
        }
        a += __shfl_xor(a, 1);
        if (!half) sc[s2] = (src_tokens[nb * SS + s2] == 0) ? -1e30f : a;
      }
      __syncthreads();
      if (tid < 64) {
        float m = fmaxf(sc[tid], sc[tid + 64]);
        for (int off = 32; off; off >>= 1) m = fmaxf(m, __shfl_xor(m, off));
        float e0 = __expf(sc[tid] - m), e1 = __expf(sc[tid + 64] - m);
        float ssum = e0 + e1;
        for (int off = 32; off; off >>= 1) ssum += __shfl_xor(ssum, off);
        float inv = 1.f / ssum;
        sc[tid] = e0 * inv; sc[tid + 64] = e1 * inv;
      }
      __syncthreads();
      float a0 = 0.f, a1 = 0.f;
      for (int s2 = 0; s2 < 128; ++s2) {
        float p_ = sc[s2];
        const float* er = enc_out + ((size_t)s2 * 64 + nb) * 512;
        a0 += p_ * er[tid];
        a1 += p_ * er[tid + 256];
      }
      x2I[idx4(tid, nb)] = a0;
      x2I[idx4(tid + 256, nb)] = a1;
    }
    gbar(bar);
    // ---- D: output projection (tanh([ctx,h1]@attn_w^T)), feed + houts ----
    {
      const float* xb;
      if (wv < 2) xb = x2I + wv * 16384 + lane * 4;
      else        xb = x1I + (pp ^ 1) * 65536 + 32768 + (wv - 2) * 16384 + lane * 4;
      float acc[2] = {};
      mac_rows<2, 64>(xb, wrD, acc);
      pt[wv][0][lane] = acc[0];
      pt[wv][1][lane] = acc[1];
    }
    __syncthreads();
    if (tid < 128) {
      int o = nb * 2 + hi;
      float v = tanhf(pt[0][hi][bb] + pt[1][hi][bb] + pt[2][hi][bb] + pt[3][hi][bb]);
      x0I[(pp ^ 1) * 65536 + idx4(o, bb)] = v;
      houts[((size_t)t * 64 + bb) * 512 + o] = v;
    }
    if (t < TT - 1) gbar(bar);
  }
}

// ---------------------------------------------------------------------------
extern "C" void kernel_launch(void* const* d_in, const int* in_sizes, int n_in,
                              void* d_out, int out_size, void* d_ws, size_t ws_size,
                              hipStream_t stream) {
  const int*   src_tokens = (const int*)d_in[0];
  const int*   dst        = (const int*)d_in[2];
  const float* emb_in     = (const float*)d_in[3];
  const float* emb_out    = (const float*)d_in[4];
  const float* enc_w_ih0  = (const float*)d_in[5];
  const float* enc_w_ih1  = (const float*)d_in[6];
  const float* enc_w_hh   = (const float*)d_in[7];
  const float* enc_b_ih   = (const float*)d_in[8];
  const float* enc_b_hh   = (const float*)d_in[9];
  const float* dec_w_ih0  = (const float*)d_in[10];
  const float* dec_w_hh0  = (const float*)d_in[11];
  const float* dec_b_ih0  = (const float*)d_in[12];
  const float* dec_b_hh0  = (const float*)d_in[13];
  const float* dec_w_ih1  = (const float*)d_in[14];
  const float* dec_w_hh1  = (const float*)d_in[15];
  const float* dec_b_ih1  = (const float*)d_in[16];
  const float* dec_b_hh1  = (const float*)d_in[17];
  const float* attn_w     = (const float*)d_in[18];
  const float* pred_w     = (const float*)d_in[19];
  const float* pred_b     = (const float*)d_in[20];
  float* out = (float*)d_out;

  float* ws     = (float*)d_ws;
  float* bufA   = ws;                  // 4,194,304 (emb / layer0 out / dst emb / houts)
  float* GT     = ws + 4194304;        // 16,777,216 transposed gates
  float* encOut = ws + 20971520;       // 4,194,304
  float* x0I    = ws + 25165824;       // 131,072
  float* x1I    = ws + 25296896;       // 131,072
  float* x2I    = ws + 25427968;       // 32,768
  float* hI     = ws + 25460736;       // 65,536
  float* c0T    = ws + 25526272;       // 32,768
  float* c1T    = ws + 25559040;       // 32,768
  unsigned* bar = (unsigned*)(ws + 25591808);
  float* houts  = bufA;

  hipMemsetAsync(bar, 0, 2 * sizeof(unsigned), stream);
  hipMemsetAsync(x0I, 0, 32768 * sizeof(float), stream);   // feed(t=0) = 0, parity 0

  // ---- Encoder ----
  k_embed<<<dim3(8192), 128, 0, stream>>>(emb_in, src_tokens, bufA, SS);
  k_gemm<1><<<dim3(16, 64), 256, 0, stream>>>(bufA, 512, enc_w_ih0, 512, 0,
                                              enc_b_ih, enc_b_hh, GT, 2048, 512);
  enc_persist<<<dim3(NBLK), 256, 0, stream>>>(GT, enc_w_hh, hI, bufA, x0I, c0T, bar);
  k_gemm<1><<<dim3(16, 64), 256, 0, stream>>>(bufA, 512, enc_w_ih1, 512, 0,
                                              enc_b_ih + 2048, enc_b_hh + 2048, GT, 2048, 512);
  enc_persist<<<dim3(NBLK), 256, 0, stream>>>(GT, enc_w_hh + 2 * 1024 * 256, hI,
                                              encOut, x1I, c1T, bar);

  // ---- Decoder precompute (emb part of cell0 gates) ----
  k_embed<<<dim3(8192), 128, 0, stream>>>(emb_out, dst, bufA, TT);
  k_gemm<1><<<dim3(16, 64), 256, 0, stream>>>(bufA, 512, dec_w_ih0, 1024, 0,
                                              dec_b_ih0, dec_b_hh0, GT, 2048, 512);

  // ---- Decoder (persistent, 128 steps x 4 phases) ----
  dec_persist<<<dim3(NBLK), 256, 0, stream>>>(
      GT, dec_w_ih0, dec_w_hh0, dec_w_ih1, dec_w_hh1, dec_b_ih1, dec_b_hh1,
      attn_w, encOut, src_tokens, c0T, c1T, x0I, x1I, x2I, houts, bar);

  // ---- Final projection straight to [B][OUT][T] ----
  k_gemm<2><<<dim3(4, 64), 256, 0, stream>>>(houts, 512, pred_w, 512, 0,
                                             pred_b, nullptr, out, 128, 512);
}

// Round 3
// 38625.735 us; speedup vs baseline: 1.2200x; 1.2200x over previous
//
#include <hip/hip_runtime.h>
#include <hip/hip_bf16.h>

#define SS 128
#define TT 128
#define NBLK 256
#define FSTRIDE 16   // one flag per 64B cacheline

__device__ __forceinline__ float sigf(float x) { return 1.f / (1.f + __expf(-x)); }

// ---------------------------------------------------------------------------
// Device-wide barrier, flag-array style (no same-address RMW serialization).
// flags[i*FSTRIDE] = arrival generation of block i; flags[NBLK*FSTRIDE] = go word.
// Block 0 is the master: its 256 threads poll the 256 per-block flags in
// parallel, then thread 0 release-stores the go word all other blocks spin on.
__device__ __forceinline__ void gbar(unsigned* flags, unsigned gen) {
  __syncthreads();
  unsigned* go = flags + NBLK * FSTRIDE;
  int nb = blockIdx.x;
  int tid = threadIdx.x;
  if (nb == 0) {
    if (tid > 0) {
      while (__hip_atomic_load(&flags[tid * FSTRIDE], __ATOMIC_ACQUIRE,
                               __HIP_MEMORY_SCOPE_AGENT) < gen)
        __builtin_amdgcn_s_sleep(1);
    }
    __syncthreads();
    if (tid == 0)
      __hip_atomic_store(go, gen, __ATOMIC_RELEASE, __HIP_MEMORY_SCOPE_AGENT);
  } else {
    if (tid == 0) {
      __hip_atomic_store(&flags[nb * FSTRIDE], gen, __ATOMIC_RELEASE,
                         __HIP_MEMORY_SCOPE_AGENT);
      while (__hip_atomic_load(go, __ATOMIC_ACQUIRE,
                               __HIP_MEMORY_SCOPE_AGENT) < gen)
        __builtin_amdgcn_s_sleep(1);
    }
    __syncthreads();
  }
}

// interleaved-4 transposed activation layout: element (row r, batch b) at
// (r>>2)*256 + b*4 + (r&3)  -> lane b loads float4 = rows r..r+3 coalesced.
__device__ __forceinline__ int idx4(int r, int b) {
  return (r >> 2) * 256 + b * 4 + (r & 3);
}

template<int NJ, int NK4>
__device__ __forceinline__ void mac_rows(const float* __restrict__ xb,
                                         const float* const* wr, float* acc) {
#pragma unroll 2
  for (int k4 = 0; k4 < NK4; ++k4) {
    float4 xv = *(const float4*)(xb + (size_t)k4 * 256);
#pragma unroll
    for (int j = 0; j < NJ; ++j) {
      float4 w4 = *(const float4*)(wr[j] + k4 * 4);
      acc[j] += xv.x * w4.x + xv.y * w4.y + xv.z * w4.z + xv.w * w4.w;
    }
  }
}

// ---------------------------------------------------------------------------
__global__ void k_embed(const float* __restrict__ emb, const int* __restrict__ toks,
                        float* __restrict__ out, int seqlen) {
  int s = blockIdx.x >> 6, b = blockIdx.x & 63;
  int tok = toks[b * seqlen + s];
  const float4* src = (const float4*)(emb + (size_t)tok * 512);
  float4* dst = (float4*)(out + (size_t)blockIdx.x * 512);
  dst[threadIdx.x] = src[threadIdx.x];
}

// ---------------------------------------------------------------------------
// GEMM C[m][n] = X[m]·W[n] + b1[n] + b2[n].
// MODE 1: write GT[((m>>6)*ldc + n)*64 + (m&63)]   (per-timestep transposed gates)
// MODE 2: write out[((m&63)*512 + n)*128 + (m>>6)] (final [B][OUT][T])
template<int MODE>
__global__ __launch_bounds__(256) void k_gemm(
    const float* __restrict__ X, int ldx,
    const float* __restrict__ W, int ldw, int koff,
    const float* __restrict__ b1, const float* __restrict__ b2,
    float* __restrict__ C, int ldc, int K) {
  __shared__ float Xs[16][132];
  __shared__ float Ws[16][132];
  int m0 = blockIdx.y * 128, n0 = blockIdx.x * 128;
  int tx = threadIdx.x & 15, ty = threadIdx.x >> 4;
  float acc[8][8] = {};
  for (int k0 = 0; k0 < K; k0 += 16) {
    __syncthreads();
#pragma unroll
    for (int j = 0; j < 2; ++j) {
      int f4 = threadIdx.x + j * 256;
      int row = f4 >> 2, kc = (f4 & 3) * 4;
      float4 xv = *(const float4*)&X[(size_t)(m0 + row) * ldx + k0 + kc];
      Xs[kc + 0][row] = xv.x; Xs[kc + 1][row] = xv.y;
      Xs[kc + 2][row] = xv.z; Xs[kc + 3][row] = xv.w;
      float4 wv = *(const float4*)&W[(size_t)(n0 + row) * ldw + koff + k0 + kc];
      Ws[kc + 0][row] = wv.x; Ws[kc + 1][row] = wv.y;
      Ws[kc + 2][row] = wv.z; Ws[kc + 3][row] = wv.w;
    }
    __syncthreads();
#pragma unroll
    for (int kk = 0; kk < 16; ++kk) {
      float a[8], w[8];
      *(float4*)&a[0] = *(const float4*)&Xs[kk][ty * 8];
      *(float4*)&a[4] = *(const float4*)&Xs[kk][ty * 8 + 4];
      *(float4*)&w[0] = *(const float4*)&Ws[kk][tx * 8];
      *(float4*)&w[4] = *(const float4*)&Ws[kk][tx * 8 + 4];
#pragma unroll
      for (int i = 0; i < 8; ++i)
#pragma unroll
        for (int j = 0; j < 8; ++j)
          acc[i][j] += a[i] * w[j];
    }
  }
  float bias[8];
#pragma unroll
  for (int j = 0; j < 8; ++j) {
    int n = n0 + tx * 8 + j;
    bias[j] = (b1 ? b1[n] : 0.f) + (b2 ? b2[n] : 0.f);
  }
  for (int i = 0; i < 8; ++i) {
    int m = m0 + ty * 8 + i;
#pragma unroll
    for (int j = 0; j < 8; ++j) {
      int n = n0 + tx * 8 + j;
      float v = acc[i][j] + bias[j];
      if (MODE == 1)
        C[((size_t)(m >> 6) * ldc + n) * 64 + (m & 63)] = v;
      else
        C[((size_t)(m & 63) * 512 + n) * 128 + (m >> 6)] = v;
    }
  }
}

// ---------------------------------------------------------------------------
// Persistent encoder layer: 128 steps, both directions, 1 grid-sync per step.
// Block nb: dir d = nb>>7, covers gate cols {nbL + 128j} = 4 gates x hu in {nbL, nbL+128}.
// LOUT=0: lout row-major [s*64+b][512] (feeds layer-1 GEMM).
// LOUT=1: lout batch-major [b][s][512] (feeds attention; per-XCD L2 locality).
template<int LOUT>
__global__ __launch_bounds__(256, 1) void enc_persist(
    const float* __restrict__ GT,     // [128][2048][64] precomputed input gates
    const float* __restrict__ whh,    // [2][1024][256] this layer
    float* __restrict__ hI,           // [2 parity][2 dir][64 r4][256]
    float* __restrict__ lout,
    float* __restrict__ hFin,         // xI dest: rows 512 + d*256 + hu (parity 0)
    float* __restrict__ cFin,         // [512][64]
    unsigned* bar) {
  int nb = blockIdx.x;
  int d = nb >> 7, nbL = nb & 127;
  int tid = threadIdx.x;
  int lane = tid & 63;
  int wv = __builtin_amdgcn_readfirstlane(tid >> 6);
  __shared__ float pt[4][8][64];
  float creg = 0.f;
  const float* wr[8];
#pragma unroll
  for (int j = 0; j < 8; ++j)
    wr[j] = whh + ((size_t)(d * 1024 + nbL + 128 * j)) * 256 + wv * 64;

  int b = tid & 63, hi = tid >> 6;
  int hu = nbL + hi * 128;

  for (int t = 0; t < SS; ++t) {
    int pp = t & 1;
    int s = d ? (SS - 1 - t) : t;
    float gi[4];
    if (tid < 128) {   // issue the (possibly HBM) gate loads early
#pragma unroll
      for (int g = 0; g < 4; ++g)
        gi[g] = GT[((size_t)s * 2048 + d * 1024 + g * 256 + hu) * 64 + b];
    }
    if (t > 0) {
      const float* xb = hI + (pp * 2 + d) * 16384 + wv * 4096 + lane * 4;
      float acc[8] = {};
      mac_rows<8, 16>(xb, wr, acc);
#pragma unroll
      for (int j = 0; j < 8; ++j) pt[wv][j][lane] = acc[j];
    }
    __syncthreads();
    if (tid < 128) {
      float g4[4];
#pragma unroll
      for (int g = 0; g < 4; ++g) {
        float sum = gi[g];
        if (t > 0)
          sum += pt[0][2 * g + hi][b] + pt[1][2 * g + hi][b] +
                 pt[2][2 * g + hi][b] + pt[3][2 * g + hi][b];
        g4[g] = sum;
      }
      float ig = sigf(g4[0]), fg = sigf(g4[1]), gg = tanhf(g4[2]), og = sigf(g4[3]);
      creg = fg * creg + ig * gg;
      float hn = og * tanhf(creg);
      hI[((pp ^ 1) * 2 + d) * 16384 + idx4(hu, b)] = hn;
      if (LOUT == 0)
        lout[((size_t)s * 64 + b) * 512 + d * 256 + hu] = hn;
      else
        lout[(size_t)b * 65536 + (size_t)s * 512 + d * 256 + hu] = hn;
      if (t == SS - 1) {
        hFin[idx4(512 + d * 256 + hu, b)] = hn;
        cFin[(d * 256 + hu) * 64 + b] = creg;
      }
    }
    if (t < SS - 1) gbar(bar, (unsigned)(t + 1));
  }
}

// ---------------------------------------------------------------------------
// Persistent decoder: 128 steps x 4 phases (cell0, cell1, attention, outproj).
__global__ __launch_bounds__(256, 1) void dec_persist(
    const float* __restrict__ GdT,    // [128][2048][64] emb gates (+biases)
    const float* __restrict__ w_ih0,  // [2048][1024]
    const float* __restrict__ w_hh0,  // [2048][512]
    const float* __restrict__ w_ih1,  // [2048][512]
    const float* __restrict__ w_hh1,  // [2048][512]
    const float* __restrict__ b_ih1, const float* __restrict__ b_hh1,
    const float* __restrict__ attn_w, // [512][1024]
    const float* __restrict__ enc_out,// [64][128][512] batch-major
    const int* __restrict__ src_tokens,
    const float* __restrict__ c0T, const float* __restrict__ c1T,  // [512][64]
    float* __restrict__ x0I,          // [2][256 r4][256]: rows 0-511 feed, 512-1023 h0
    float* __restrict__ x1I,          // [2][256 r4][256]: rows 0-511 h0cur, 512-1023 h1
    float* __restrict__ x2I,          // [128 r4][256]: ctx
    float* __restrict__ houts,        // [8192][512] row-major
    unsigned* bar) {
  int nb = blockIdx.x;
  int tid = threadIdx.x;
  int lane = tid & 63;
  int wv = __builtin_amdgcn_readfirstlane(tid >> 6);
  __shared__ float pt[4][8][64];
  __shared__ float h1s[512];
  __shared__ float sc[128];

  int bb = tid & 63, hi = tid >> 6;
  int hu = nb + (hi & 1) * 256;
  float c0r = 0.f, c1r = 0.f;
  if (tid < 128) { c0r = c0T[hu * 64 + bb]; c1r = c1T[hu * 64 + bb]; }

  const float* wrA[8]; const float* wrB[8]; const float* wrD[2];
  if (wv < 2) {
#pragma unroll
    for (int j = 0; j < 8; ++j) {
      wrA[j] = w_ih0 + (size_t)(nb + 256 * j) * 1024 + 512 + wv * 256;
      wrB[j] = w_ih1 + (size_t)(nb + 256 * j) * 512 + wv * 256;
    }
#pragma unroll
    for (int j = 0; j < 2; ++j)
      wrD[j] = attn_w + (size_t)(nb * 2 + j) * 1024 + wv * 256;
  } else {
#pragma unroll
    for (int j = 0; j < 8; ++j) {
      wrA[j] = w_hh0 + (size_t)(nb + 256 * j) * 512 + (wv - 2) * 256;
      wrB[j] = w_hh1 + (size_t)(nb + 256 * j) * 512 + (wv - 2) * 256;
    }
#pragma unroll
    for (int j = 0; j < 2; ++j)
      wrD[j] = attn_w + (size_t)(nb * 2 + j) * 1024 + 512 + (wv - 2) * 256;
  }

  for (int t = 0; t < TT; ++t) {
    int pp = t & 1;
    unsigned gb = (unsigned)(t * 4);
    // ---- A: cell0 gates ----
    float giA[4];
    if (tid < 128) {   // issue HBM gate loads early
#pragma unroll
      for (int g = 0; g < 4; ++g)
        giA[g] = GdT[((size_t)t * 2048 + g * 512 + hu) * 64 + bb];
    }
    {
      const float* xb = x0I + pp * 65536 + wv * 16384 + lane * 4;
      float acc[8] = {};
      mac_rows<8, 64>(xb, wrA, acc);
#pragma unroll
      for (int j = 0; j < 8; ++j) pt[wv][j][lane] = acc[j];
    }
    __syncthreads();
    if (tid < 128) {
      float g4[4];
#pragma unroll
      for (int g = 0; g < 4; ++g)
        g4[g] = pt[0][2 * g + hi][bb] + pt[1][2 * g + hi][bb] +
                pt[2][2 * g + hi][bb] + pt[3][2 * g + hi][bb] + giA[g];
      float ig = sigf(g4[0]), fg = sigf(g4[1]), gg = tanhf(g4[2]), og = sigf(g4[3]);
      c0r = fg * c0r + ig * gg;
      float hn = og * tanhf(c0r);
      x0I[(pp ^ 1) * 65536 + idx4(512 + hu, bb)] = hn;
      x1I[pp * 65536 + idx4(hu, bb)] = hn;
    }
    gbar(bar, gb + 1);
    // ---- B: cell1 gates ----
    {
      const float* xb = x1I + pp * 65536 + wv * 16384 + lane * 4;
      float acc[8] = {};
      mac_rows<8, 64>(xb, wrB, acc);
#pragma unroll
      for (int j = 0; j < 8; ++j) pt[wv][j][lane] = acc[j];
    }
    __syncthreads();
    if (tid < 128) {
      float g4[4];
#pragma unroll
      for (int g = 0; g < 4; ++g)
        g4[g] = pt[0][2 * g + hi][bb] + pt[1][2 * g + hi][bb] +
                pt[2][2 * g + hi][bb] + pt[3][2 * g + hi][bb] +
                b_ih1[g * 512 + hu] + b_hh1[g * 512 + hu];
      float ig = sigf(g4[0]), fg = sigf(g4[1]), gg = tanhf(g4[2]), og = sigf(g4[3]);
      c1r = fg * c1r + ig * gg;
      float hn = og * tanhf(c1r);
      x1I[(pp ^ 1) * 65536 + idx4(512 + hu, bb)] = hn;
    }
    gbar(bar, gb + 2);
    // ---- C: attention (blocks 0..63, one per batch; enc_out [b][s][h]) ----
    if (nb < 64) {
      const float* x1c = x1I + (pp ^ 1) * 65536;
      const float* eb = enc_out + (size_t)nb * 65536;
      for (int i = tid; i < 512; i += 256)
        h1s[i] = x1c[idx4(512 + i, nb)];
      __syncthreads();
      {
        int s2 = tid >> 1, half = tid & 1;
        const float* er = eb + (size_t)s2 * 512 + half * 256;
        const float* hh = h1s + half * 256;
        float a = 0.f;
#pragma unroll 8
        for (int k = 0; k < 256; k += 4) {
          float4 ev = *(const float4*)&er[k];
          a += ev.x * hh[k] + ev.y * hh[k + 1] + ev.z * hh[k + 2] + ev.w * hh[k + 3];
        }
        a += __shfl_xor(a, 1);
        if (!half) sc[s2] = (src_tokens[nb * SS + s2] == 0) ? -1e30f : a;
      }
      __syncthreads();
      if (tid < 64) {
        float m = fmaxf(sc[tid], sc[tid + 64]);
        for (int off = 32; off; off >>= 1) m = fmaxf(m, __shfl_xor(m, off));
        float e0 = __expf(sc[tid] - m), e1 = __expf(sc[tid + 64] - m);
        float ssum = e0 + e1;
        for (int off = 32; off; off >>= 1) ssum += __shfl_xor(ssum, off);
        float inv = 1.f / ssum;
        sc[tid] = e0 * inv; sc[tid + 64] = e1 * inv;
      }
      __syncthreads();
      float a0 = 0.f, a1 = 0.f;
      for (int s2 = 0; s2 < 128; ++s2) {
        float p_ = sc[s2];
        const float* er = eb + (size_t)s2 * 512;
        a0 += p_ * er[tid];
        a1 += p_ * er[tid + 256];
      }
      x2I[idx4(tid, nb)] = a0;
      x2I[idx4(tid + 256, nb)] = a1;
    }
    gbar(bar, gb + 3);
    // ---- D: output projection tanh([ctx,h1]@attn_w^T) -> feed + houts ----
    {
      const float* xb;
      if (wv < 2) xb = x2I + wv * 16384 + lane * 4;
      else        xb = x1I + (pp ^ 1) * 65536 + 32768 + (wv - 2) * 16384 + lane * 4;
      float acc[2] = {};
      mac_rows<2, 64>(xb, wrD, acc);
      pt[wv][0][lane] = acc[0];
      pt[wv][1][lane] = acc[1];
    }
    __syncthreads();
    if (tid < 128) {
      int o = nb * 2 + hi;
      float v = tanhf(pt[0][hi][bb] + pt[1][hi][bb] + pt[2][hi][bb] + pt[3][hi][bb]);
      x0I[(pp ^ 1) * 65536 + idx4(o, bb)] = v;
      houts[((size_t)t * 64 + bb) * 512 + o] = v;
    }
    if (t < TT - 1) gbar(bar, gb + 4);
  }
}

// ---------------------------------------------------------------------------
extern "C" void kernel_launch(void* const* d_in, const int* in_sizes, int n_in,
                              void* d_out, int out_size, void* d_ws, size_t ws_size,
                              hipStream_t stream) {
  const int*   src_tokens = (const int*)d_in[0];
  const int*   dst        = (const int*)d_in[2];
  const float* emb_in     = (const float*)d_in[3];
  const float* emb_out    = (const float*)d_in[4];
  const float* enc_w_ih0  = (const float*)d_in[5];
  const float* enc_w_ih1  = (const float*)d_in[6];
  const float* enc_w_hh   = (const float*)d_in[7];
  const float* enc_b_ih   = (const float*)d_in[8];
  const float* enc_b_hh   = (const float*)d_in[9];
  const float* dec_w_ih0  = (const float*)d_in[10];
  const float* dec_w_hh0  = (const float*)d_in[11];
  const float* dec_b_ih0  = (const float*)d_in[12];
  const float* dec_b_hh0  = (const float*)d_in[13];
  const float* dec_w_ih1  = (const float*)d_in[14];
  const float* dec_w_hh1  = (const float*)d_in[15];
  const float* dec_b_ih1  = (const float*)d_in[16];
  const float* dec_b_hh1  = (const float*)d_in[17];
  const float* attn_w     = (const float*)d_in[18];
  const float* pred_w     = (const float*)d_in[19];
  const float* pred_b     = (const float*)d_in[20];
  float* out = (float*)d_out;

  float* ws     = (float*)d_ws;
  float* bufA   = ws;                  // 4,194,304 (emb / layer0 out / dst emb / houts)
  float* GT     = ws + 4194304;        // 16,777,216 transposed gates
  float* encOut = ws + 20971520;       // 4,194,304 ([b][s][h])
  float* x0I    = ws + 25165824;       // 131,072
  float* x1I    = ws + 25296896;       // 131,072
  float* x2I    = ws + 25427968;       // 32,768
  float* hI     = ws + 25460736;       // 65,536
  float* c0T    = ws + 25526272;       // 32,768
  float* c1T    = ws + 25559040;       // 32,768
  unsigned* barA = (unsigned*)(ws + 25591808);   // 3 x 8192 uints
  unsigned* barB = barA + 8192;
  unsigned* barC = barB + 8192;
  float* houts  = bufA;

  hipMemsetAsync(barA, 0, 3 * 8192 * sizeof(unsigned), stream);
  hipMemsetAsync(x0I, 0, 32768 * sizeof(float), stream);   // feed(t=0)=0, parity 0

  // ---- Encoder ----
  k_embed<<<dim3(8192), 128, 0, stream>>>(emb_in, src_tokens, bufA, SS);
  k_gemm<1><<<dim3(16, 64), 256, 0, stream>>>(bufA, 512, enc_w_ih0, 512, 0,
                                              enc_b_ih, enc_b_hh, GT, 2048, 512);
  enc_persist<0><<<dim3(NBLK), 256, 0, stream>>>(GT, enc_w_hh, hI, bufA, x0I, c0T, barA);
  k_gemm<1><<<dim3(16, 64), 256, 0, stream>>>(bufA, 512, enc_w_ih1, 512, 0,
                                              enc_b_ih + 2048, enc_b_hh + 2048, GT, 2048, 512);
  enc_persist<1><<<dim3(NBLK), 256, 0, stream>>>(GT, enc_w_hh + 2 * 1024 * 256, hI,
                                                 encOut, x1I, c1T, barB);

  // ---- Decoder precompute (emb part of cell0 gates) ----
  k_embed<<<dim3(8192), 128, 0, stream>>>(emb_out, dst, bufA, TT);
  k_gemm<1><<<dim3(16, 64), 256, 0, stream>>>(bufA, 512, dec_w_ih0, 1024, 0,
                                              dec_b_ih0, dec_b_hh0, GT, 2048, 512);

  // ---- Decoder (persistent, 128 steps x 4 phases) ----
  dec_persist<<<dim3(NBLK), 256, 0, stream>>>(
      GT, dec_w_ih0, dec_w_hh0, dec_w_ih1, dec_w_hh1, dec_b_ih1, dec_b_hh1,
      attn_w, encOut, src_tokens, c0T, c1T, x0I, x1I, x2I, houts, barC);

  // ---- Final projection straight to [B][OUT][T] ----
  k_gemm<2><<<dim3(4, 64), 256, 0, stream>>>(houts, 512, pred_w, 512, 0,
                                             pred_b, nullptr, out, 128, 512);
}

// Round 4
// 13923.361 us; speedup vs baseline: 3.3845x; 2.7742x over previous
//
#include <hip/hip_runtime.h>
#include <hip/hip_bf16.h>

#define SS 128
#define TT 128
#define NBLK 256
#define FSTRIDE 16   // one flag per 64B cacheline

__device__ __forceinline__ float sigf(float x) { return 1.f / (1.f + __expf(-x)); }

// Coherent (MALL-level) scalar access for cross-block data. RELAXED+AGENT
// compiles to sc0/sc1 load/store: bypasses (possibly stale) L1/L2, NO cache
// invalidation side effects -> weights stay L2-resident across barriers.
__device__ __forceinline__ float cload(const float* p) {
  return __hip_atomic_load(p, __ATOMIC_RELAXED, __HIP_MEMORY_SCOPE_AGENT);
}
__device__ __forceinline__ void cstore(float* p, float v) {
  __hip_atomic_store(p, v, __ATOMIC_RELAXED, __HIP_MEMORY_SCOPE_AGENT);
}

// ---------------------------------------------------------------------------
// Device-wide barrier WITHOUT acquire-invalidate. Data moves via cload/cstore
// (coherent at MALL); flags: arrive=RELEASE (vmcnt drain + wb, no invalidate),
// polls=RELAXED. __syncthreads before arrival drains all waves' stores.
__device__ __forceinline__ void gbar(unsigned* flags, unsigned gen) {
  __syncthreads();
  unsigned* go = flags + NBLK * FSTRIDE;
  int tid = threadIdx.x;
  if (blockIdx.x == 0) {
    if (tid > 0) {
      int guard = 0;
      while (__hip_atomic_load(&flags[tid * FSTRIDE], __ATOMIC_RELAXED,
                               __HIP_MEMORY_SCOPE_AGENT) < gen &&
             ++guard < (1 << 20))
        __builtin_amdgcn_s_sleep(1);
    }
    __syncthreads();
    if (tid == 0)
      __hip_atomic_store(go, gen, __ATOMIC_RELEASE, __HIP_MEMORY_SCOPE_AGENT);
  } else {
    if (tid == 0) {
      __hip_atomic_store(&flags[blockIdx.x * FSTRIDE], gen, __ATOMIC_RELEASE,
                         __HIP_MEMORY_SCOPE_AGENT);
      int guard = 0;
      while (__hip_atomic_load(go, __ATOMIC_RELAXED,
                               __HIP_MEMORY_SCOPE_AGENT) < gen &&
             ++guard < (1 << 20))
        __builtin_amdgcn_s_sleep(1);
    }
    __syncthreads();
  }
  asm volatile("" ::: "memory");
}

// ---------------------------------------------------------------------------
// x buffers are plain [row][64 batch]. Lane = batch. Weights (wave-uniform
// rows) come from plain cached loads (s_load, L2-resident).
// xb = buffer_base + wave_k_offset*64 + lane ; k4 walks 4 rows at a time.
template<int NJ, int NK4>
__device__ __forceinline__ void mac_rows(const float* __restrict__ xb,
                                         const float* const* wr, float* acc) {
#pragma unroll 4
  for (int k4 = 0; k4 < NK4; ++k4) {
    float x0 = cload(xb + k4 * 256);
    float x1 = cload(xb + k4 * 256 + 64);
    float x2 = cload(xb + k4 * 256 + 128);
    float x3 = cload(xb + k4 * 256 + 192);
#pragma unroll
    for (int j = 0; j < NJ; ++j) {
      float4 w4 = *(const float4*)(wr[j] + k4 * 4);
      acc[j] += x0 * w4.x + x1 * w4.y + x2 * w4.z + x3 * w4.w;
    }
  }
}

// ---------------------------------------------------------------------------
__global__ void k_embed(const float* __restrict__ emb, const int* __restrict__ toks,
                        float* __restrict__ out, int seqlen) {
  int s = blockIdx.x >> 6, b = blockIdx.x & 63;
  int tok = toks[b * seqlen + s];
  const float4* src = (const float4*)(emb + (size_t)tok * 512);
  float4* dst = (float4*)(out + (size_t)blockIdx.x * 512);
  dst[threadIdx.x] = src[threadIdx.x];
}

// ---------------------------------------------------------------------------
// GEMM C[m][n] = X[m]·W[n] + b1[n] + b2[n].
// MODE 1: write GT[((m>>6)*ldc + n)*64 + (m&63)]   (per-timestep transposed gates)
// MODE 2: write out[((m&63)*512 + n)*128 + (m>>6)] (final [B][OUT][T])
template<int MODE>
__global__ __launch_bounds__(256) void k_gemm(
    const float* __restrict__ X, int ldx,
    const float* __restrict__ W, int ldw, int koff,
    const float* __restrict__ b1, const float* __restrict__ b2,
    float* __restrict__ C, int ldc, int K) {
  __shared__ float Xs[16][132];
  __shared__ float Ws[16][132];
  int m0 = blockIdx.y * 128, n0 = blockIdx.x * 128;
  int tx = threadIdx.x & 15, ty = threadIdx.x >> 4;
  float acc[8][8] = {};
  for (int k0 = 0; k0 < K; k0 += 16) {
    __syncthreads();
#pragma unroll
    for (int j = 0; j < 2; ++j) {
      int f4 = threadIdx.x + j * 256;
      int row = f4 >> 2, kc = (f4 & 3) * 4;
      float4 xv = *(const float4*)&X[(size_t)(m0 + row) * ldx + k0 + kc];
      Xs[kc + 0][row] = xv.x; Xs[kc + 1][row] = xv.y;
      Xs[kc + 2][row] = xv.z; Xs[kc + 3][row] = xv.w;
      float4 wv = *(const float4*)&W[(size_t)(n0 + row) * ldw + koff + k0 + kc];
      Ws[kc + 0][row] = wv.x; Ws[kc + 1][row] = wv.y;
      Ws[kc + 2][row] = wv.z; Ws[kc + 3][row] = wv.w;
    }
    __syncthreads();
#pragma unroll
    for (int kk = 0; kk < 16; ++kk) {
      float a[8], w[8];
      *(float4*)&a[0] = *(const float4*)&Xs[kk][ty * 8];
      *(float4*)&a[4] = *(const float4*)&Xs[kk][ty * 8 + 4];
      *(float4*)&w[0] = *(const float4*)&Ws[kk][tx * 8];
      *(float4*)&w[4] = *(const float4*)&Ws[kk][tx * 8 + 4];
#pragma unroll
      for (int i = 0; i < 8; ++i)
#pragma unroll
        for (int j = 0; j < 8; ++j)
          acc[i][j] += a[i] * w[j];
    }
  }
  float bias[8];
#pragma unroll
  for (int j = 0; j < 8; ++j) {
    int n = n0 + tx * 8 + j;
    bias[j] = (b1 ? b1[n] : 0.f) + (b2 ? b2[n] : 0.f);
  }
  for (int i = 0; i < 8; ++i) {
    int m = m0 + ty * 8 + i;
#pragma unroll
    for (int j = 0; j < 8; ++j) {
      int n = n0 + tx * 8 + j;
      float v = acc[i][j] + bias[j];
      if (MODE == 1)
        C[((size_t)(m >> 6) * ldc + n) * 64 + (m & 63)] = v;
      else
        C[((size_t)(m & 63) * 512 + n) * 128 + (m >> 6)] = v;
    }
  }
}

// ---------------------------------------------------------------------------
// Persistent encoder layer: 128 steps, both directions, 1 grid-sync per step.
// Block nb: dir d = nb>>7, gate cols {nbL + 128j}. hI: [2 par][2 dir][256][64].
template<int LOUT>
__global__ __launch_bounds__(256, 1) void enc_persist(
    const float* __restrict__ GT,     // [128][2048][64] precomputed input gates
    const float* __restrict__ whh,    // [2][1024][256] this layer
    float* __restrict__ hI,
    float* __restrict__ lout,
    float* __restrict__ hFin,         // x buffer base; rows 512 + d*256 + hu
    float* __restrict__ cFin,         // [512][64]
    unsigned* bar) {
  int nb = blockIdx.x;
  int d = nb >> 7, nbL = nb & 127;
  int tid = threadIdx.x;
  int lane = tid & 63;
  int wv = __builtin_amdgcn_readfirstlane(tid >> 6);
  __shared__ float pt[4][8][64];
  float creg = 0.f;
  const float* wr[8];
#pragma unroll
  for (int j = 0; j < 8; ++j)
    wr[j] = whh + ((size_t)(d * 1024 + nbL + 128 * j)) * 256 + wv * 64;

  int b = tid & 63, hi = tid >> 6;
  int hu = nbL + hi * 128;

  for (int t = 0; t < SS; ++t) {
    int pp = t & 1;
    int s = d ? (SS - 1 - t) : t;
    float gi[4];
    if (tid < 128) {
#pragma unroll
      for (int g = 0; g < 4; ++g)
        gi[g] = GT[((size_t)s * 2048 + d * 1024 + g * 256 + hu) * 64 + b];
    }
    if (t > 0) {
      const float* xb = hI + (pp * 2 + d) * 16384 + wv * 4096 + lane;
      float acc[8] = {};
      mac_rows<8, 16>(xb, wr, acc);
#pragma unroll
      for (int j = 0; j < 8; ++j) pt[wv][j][lane] = acc[j];
    }
    __syncthreads();
    if (tid < 128) {
      float g4[4];
#pragma unroll
      for (int g = 0; g < 4; ++g) {
        float sum = gi[g];
        if (t > 0)
          sum += pt[0][2 * g + hi][b] + pt[1][2 * g + hi][b] +
                 pt[2][2 * g + hi][b] + pt[3][2 * g + hi][b];
        g4[g] = sum;
      }
      float ig = sigf(g4[0]), fg = sigf(g4[1]), gg = tanhf(g4[2]), og = sigf(g4[3]);
      creg = fg * creg + ig * gg;
      float hn = og * tanhf(creg);
      cstore(&hI[((pp ^ 1) * 2 + d) * 16384 + hu * 64 + b], hn);
      if (LOUT == 0)
        lout[((size_t)s * 64 + b) * 512 + d * 256 + hu] = hn;
      else
        lout[(size_t)b * 65536 + (size_t)s * 512 + d * 256 + hu] = hn;
      if (t == SS - 1) {
        cstore(&hFin[(512 + d * 256 + hu) * 64 + b], hn);
        cFin[(d * 256 + hu) * 64 + b] = creg;
      }
    }
    if (t < SS - 1) gbar(bar, (unsigned)(t + 1));
  }
}

// ---------------------------------------------------------------------------
// Persistent decoder: 128 steps x 4 phases (cell0, cell1, attention, outproj).
// x0I/x1I: [2 parity][1024][64]; x2I: [512][64] (ctx).
__global__ __launch_bounds__(256, 1) void dec_persist(
    const float* __restrict__ GdT,    // [128][2048][64] emb gates (+biases)
    const float* __restrict__ w_ih0,  // [2048][1024]
    const float* __restrict__ w_hh0,  // [2048][512]
    const float* __restrict__ w_ih1,  // [2048][512]
    const float* __restrict__ w_hh1,  // [2048][512]
    const float* __restrict__ b_ih1, const float* __restrict__ b_hh1,
    const float* __restrict__ attn_w, // [512][1024]
    const float* __restrict__ enc_out,// [64][128][512] batch-major
    const int* __restrict__ src_tokens,
    const float* __restrict__ c0T, const float* __restrict__ c1T,  // [512][64]
    float* __restrict__ x0I,
    float* __restrict__ x1I,
    float* __restrict__ x2I,
    float* __restrict__ houts,        // [8192][512] row-major
    unsigned* bar) {
  int nb = blockIdx.x;
  int tid = threadIdx.x;
  int lane = tid & 63;
  int wv = __builtin_amdgcn_readfirstlane(tid >> 6);
  __shared__ float pt[4][8][64];
  __shared__ float h1s[512];
  __shared__ float sc[128];

  int bb = tid & 63, hi = tid >> 6;
  int hu = nb + (hi & 1) * 256;
  float c0r = 0.f, c1r = 0.f;
  if (tid < 128) { c0r = c0T[hu * 64 + bb]; c1r = c1T[hu * 64 + bb]; }

  const float* wrA[8]; const float* wrB[8]; const float* wrD[2];
  if (wv < 2) {
#pragma unroll
    for (int j = 0; j < 8; ++j) {
      wrA[j] = w_ih0 + (size_t)(nb + 256 * j) * 1024 + 512 + wv * 256;
      wrB[j] = w_ih1 + (size_t)(nb + 256 * j) * 512 + wv * 256;
    }
#pragma unroll
    for (int j = 0; j < 2; ++j)
      wrD[j] = attn_w + (size_t)(nb * 2 + j) * 1024 + wv * 256;
  } else {
#pragma unroll
    for (int j = 0; j < 8; ++j) {
      wrA[j] = w_hh0 + (size_t)(nb + 256 * j) * 512 + (wv - 2) * 256;
      wrB[j] = w_hh1 + (size_t)(nb + 256 * j) * 512 + (wv - 2) * 256;
    }
#pragma unroll
    for (int j = 0; j < 2; ++j)
      wrD[j] = attn_w + (size_t)(nb * 2 + j) * 1024 + 512 + (wv - 2) * 256;
  }

  for (int t = 0; t < TT; ++t) {
    int pp = t & 1;
    unsigned gb = (unsigned)(t * 4);
    // ---- A: cell0 gates ----
    float giA[4];
    if (tid < 128) {
#pragma unroll
      for (int g = 0; g < 4; ++g)
        giA[g] = GdT[((size_t)t * 2048 + g * 512 + hu) * 64 + bb];
    }
    {
      const float* xb = x0I + pp * 65536 + wv * 16384 + lane;
      float acc[8] = {};
      mac_rows<8, 64>(xb, wrA, acc);
#pragma unroll
      for (int j = 0; j < 8; ++j) pt[wv][j][lane] = acc[j];
    }
    __syncthreads();
    if (tid < 128) {
      float g4[4];
#pragma unroll
      for (int g = 0; g < 4; ++g)
        g4[g] = pt[0][2 * g + hi][bb] + pt[1][2 * g + hi][bb] +
                pt[2][2 * g + hi][bb] + pt[3][2 * g + hi][bb] + giA[g];
      float ig = sigf(g4[0]), fg = sigf(g4[1]), gg = tanhf(g4[2]), og = sigf(g4[3]);
      c0r = fg * c0r + ig * gg;
      float hn = og * tanhf(c0r);
      cstore(&x0I[(pp ^ 1) * 65536 + (512 + hu) * 64 + bb], hn);
      cstore(&x1I[pp * 65536 + hu * 64 + bb], hn);
    }
    gbar(bar, gb + 1);
    // ---- B: cell1 gates ----
    {
      const float* xb = x1I + pp * 65536 + wv * 16384 + lane;
      float acc[8] = {};
      mac_rows<8, 64>(xb, wrB, acc);
#pragma unroll
      for (int j = 0; j < 8; ++j) pt[wv][j][lane] = acc[j];
    }
    __syncthreads();
    if (tid < 128) {
      float g4[4];
#pragma unroll
      for (int g = 0; g < 4; ++g)
        g4[g] = pt[0][2 * g + hi][bb] + pt[1][2 * g + hi][bb] +
                pt[2][2 * g + hi][bb] + pt[3][2 * g + hi][bb] +
                b_ih1[g * 512 + hu] + b_hh1[g * 512 + hu];
      float ig = sigf(g4[0]), fg = sigf(g4[1]), gg = tanhf(g4[2]), og = sigf(g4[3]);
      c1r = fg * c1r + ig * gg;
      float hn = og * tanhf(c1r);
      cstore(&x1I[(pp ^ 1) * 65536 + (512 + hu) * 64 + bb], hn);
    }
    gbar(bar, gb + 2);
    // ---- C: attention (blocks 0..63, one per batch; enc_out [b][s][h]) ----
    if (nb < 64) {
      const float* x1c = x1I + (pp ^ 1) * 65536;
      const float* eb = enc_out + (size_t)nb * 65536;
      for (int i = tid; i < 512; i += 256)
        h1s[i] = cload(x1c + (512 + i) * 64 + nb);
      __syncthreads();
      {
        int s2 = tid >> 1, half = tid & 1;
        const float* er = eb + (size_t)s2 * 512 + half * 256;
        const float* hh = h1s + half * 256;
        float a = 0.f;
#pragma unroll 8
        for (int k = 0; k < 256; k += 4) {
          float4 ev = *(const float4*)&er[k];
          a += ev.x * hh[k] + ev.y * hh[k + 1] + ev.z * hh[k + 2] + ev.w * hh[k + 3];
        }
        a += __shfl_xor(a, 1);
        if (!half) sc[s2] = (src_tokens[nb * SS + s2] == 0) ? -1e30f : a;
      }
      __syncthreads();
      if (tid < 64) {
        float m = fmaxf(sc[tid], sc[tid + 64]);
        for (int off = 32; off; off >>= 1) m = fmaxf(m, __shfl_xor(m, off));
        float e0 = __expf(sc[tid] - m), e1 = __expf(sc[tid + 64] - m);
        float ssum = e0 + e1;
        for (int off = 32; off; off >>= 1) ssum += __shfl_xor(ssum, off);
        float inv = 1.f / ssum;
        sc[tid] = e0 * inv; sc[tid + 64] = e1 * inv;
      }
      __syncthreads();
      float a0 = 0.f, a1 = 0.f;
      for (int s2 = 0; s2 < 128; ++s2) {
        float p_ = sc[s2];
        const float* er = eb + (size_t)s2 * 512;
        a0 += p_ * er[tid];
        a1 += p_ * er[tid + 256];
      }
      cstore(&x2I[tid * 64 + nb], a0);
      cstore(&x2I[(tid + 256) * 64 + nb], a1);
    }
    gbar(bar, gb + 3);
    // ---- D: output projection tanh([ctx,h1]@attn_w^T) -> feed + houts ----
    {
      const float* xb;
      if (wv < 2) xb = x2I + wv * 16384 + lane;
      else        xb = x1I + (pp ^ 1) * 65536 + 32768 + (wv - 2) * 16384 + lane;
      float acc[2] = {};
      mac_rows<2, 64>(xb, wrD, acc);
      pt[wv][0][lane] = acc[0];
      pt[wv][1][lane] = acc[1];
    }
    __syncthreads();
    if (tid < 128) {
      int o = nb * 2 + hi;
      float v = tanhf(pt[0][hi][bb] + pt[1][hi][bb] + pt[2][hi][bb] + pt[3][hi][bb]);
      cstore(&x0I[(pp ^ 1) * 65536 + o * 64 + bb], v);
      houts[((size_t)t * 64 + bb) * 512 + o] = v;
    }
    if (t < TT - 1) gbar(bar, gb + 4);
  }
}

// ---------------------------------------------------------------------------
extern "C" void kernel_launch(void* const* d_in, const int* in_sizes, int n_in,
                              void* d_out, int out_size, void* d_ws, size_t ws_size,
                              hipStream_t stream) {
  const int*   src_tokens = (const int*)d_in[0];
  const int*   dst        = (const int*)d_in[2];
  const float* emb_in     = (const float*)d_in[3];
  const float* emb_out    = (const float*)d_in[4];
  const float* enc_w_ih0  = (const float*)d_in[5];
  const float* enc_w_ih1  = (const float*)d_in[6];
  const float* enc_w_hh   = (const float*)d_in[7];
  const float* enc_b_ih   = (const float*)d_in[8];
  const float* enc_b_hh   = (const float*)d_in[9];
  const float* dec_w_ih0  = (const float*)d_in[10];
  const float* dec_w_hh0  = (const float*)d_in[11];
  const float* dec_b_ih0  = (const float*)d_in[12];
  const float* dec_b_hh0  = (const float*)d_in[13];
  const float* dec_w_ih1  = (const float*)d_in[14];
  const float* dec_w_hh1  = (const float*)d_in[15];
  const float* dec_b_ih1  = (const float*)d_in[16];
  const float* dec_b_hh1  = (const float*)d_in[17];
  const float* attn_w     = (const float*)d_in[18];
  const float* pred_w     = (const float*)d_in[19];
  const float* pred_b     = (const float*)d_in[20];
  float* out = (float*)d_out;

  float* ws     = (float*)d_ws;
  float* bufA   = ws;                  // 4,194,304 (emb / layer0 out / dst emb / houts)
  float* GT     = ws + 4194304;        // 16,777,216 transposed gates
  float* encOut = ws + 20971520;       // 4,194,304 ([b][s][h])
  float* x0I    = ws + 25165824;       // 131,072
  float* x1I    = ws + 25296896;       // 131,072
  float* x2I    = ws + 25427968;       // 32,768
  float* hI     = ws + 25460736;       // 65,536
  float* c0T    = ws + 25526272;       // 32,768
  float* c1T    = ws + 25559040;       // 32,768
  unsigned* barA = (unsigned*)(ws + 25591808);   // 3 x 8192 uints
  unsigned* barB = barA + 8192;
  unsigned* barC = barB + 8192;
  float* houts  = bufA;

  hipMemsetAsync(barA, 0, 3 * 8192 * sizeof(unsigned), stream);
  hipMemsetAsync(x0I, 0, 32768 * sizeof(float), stream);   // feed(t=0)=0, parity 0

  // ---- Encoder ----
  k_embed<<<dim3(8192), 128, 0, stream>>>(emb_in, src_tokens, bufA, SS);
  k_gemm<1><<<dim3(16, 64), 256, 0, stream>>>(bufA, 512, enc_w_ih0, 512, 0,
                                              enc_b_ih, enc_b_hh, GT, 2048, 512);
  enc_persist<0><<<dim3(NBLK), 256, 0, stream>>>(GT, enc_w_hh, hI, bufA, x0I, c0T, barA);
  k_gemm<1><<<dim3(16, 64), 256, 0, stream>>>(bufA, 512, enc_w_ih1, 512, 0,
                                              enc_b_ih + 2048, enc_b_hh + 2048, GT, 2048, 512);
  enc_persist<1><<<dim3(NBLK), 256, 0, stream>>>(GT, enc_w_hh + 2 * 1024 * 256, hI,
                                                 encOut, x1I, c1T, barB);

  // ---- Decoder precompute (emb part of cell0 gates) ----
  k_embed<<<dim3(8192), 128, 0, stream>>>(emb_out, dst, bufA, TT);
  k_gemm<1><<<dim3(16, 64), 256, 0, stream>>>(bufA, 512, dec_w_ih0, 1024, 0,
                                              dec_b_ih0, dec_b_hh0, GT, 2048, 512);

  // ---- Decoder (persistent, 128 steps x 4 phases) ----
  dec_persist<<<dim3(NBLK), 256, 0, stream>>>(
      GT, dec_w_ih0, dec_w_hh0, dec_w_ih1, dec_w_hh1, dec_b_ih1, dec_b_hh1,
      attn_w, encOut, src_tokens, c0T, c1T, x0I, x1I, x2I, houts, barC);

  // ---- Final projection straight to [B][OUT][T] ----
  k_gemm<2><<<dim3(4, 64), 256, 0, stream>>>(houts, 512, pred_w, 512, 0,
                                             pred_b, nullptr, out, 128, 512);
}